// Round 16
// baseline (237.480 us; speedup 1.0000x reference)
//
#include <hip/hip_runtime.h>

#define NPTS 4096
#define NB 4
#define NROWS (NB*NPTS)       // 16384
#define EPSV 1e-5f
#define THR 1.067f            // d2 cutoff: sim==+0.0 exactly for d2>1.0667 (h^2 underflow)
#define C2 (-72.134752f)      // -50*log2(e); sim = (2^(C2*d))^2 = exp(-100 d)
#define DSCALE 61900.0f       // d in [0,1.0333) -> u16 (max 63958)
#define DINV (1.0f/61900.0f)
#define CDQ (C2*DINV)         // exp2 arg per d_q count
#define ZMARG 1.05f           // z prune margin: sqrt(1.067)=1.033 + bin disorder
#define PHCOLS 2048           // columns per fill tile phase
#define DUMMY 0xFFFF0000u     // dq=65535 -> sim==+0.0 exactly; j=0

typedef unsigned short u16;
typedef unsigned int u32;
typedef unsigned long long ull;

__device__ __forceinline__ float quad_d2(float4 a, float4 g) {
    float cr = fmaf(a.z, g.z, fmaf(a.y, g.y, a.x * g.x));
    return fmaf(-2.0f, cr, a.w + g.w);  // pinned FMA pattern, identical everywhere
}

// ---------------- sort: per batch+side, counting-sort by z, pack float4 -----
__global__ __launch_bounds__(1024) void sort_kernel(
        const float* __restrict__ pred, const float* __restrict__ gt,
        float4* __restrict__ A4s, float4* __restrict__ B4s) {
    __shared__ int hist[1024];
    int tid = threadIdx.x;
    int b = blockIdx.x >> 1, side = blockIdx.x & 1;
    const float* src = side ? gt : pred;
    float4* dst = side ? B4s : A4s;
    int cb = b * NPTS;
    float4 p[4]; int key[4];
    hist[tid] = 0;
    __syncthreads();
    #pragma unroll
    for (int k = 0; k < 4; ++k) {
        int idx = cb + k*1024 + tid;
        float x = src[3*idx], y = src[3*idx+1], z = src[3*idx+2];
        p[k] = make_float4(x, y, z, (x*x + y*y) + z*z);
        key[k] = (int)fminf(fmaxf((z + 5.0f) * 102.3f, 0.0f), 1023.0f);
        atomicAdd(&hist[key[k]], 1);
    }
    __syncthreads();
    int h0 = hist[tid];
    __syncthreads();
    for (int off = 1; off < 1024; off <<= 1) {
        int x = (tid >= off) ? hist[tid - off] : 0;
        __syncthreads();
        hist[tid] += x;
        __syncthreads();
    }
    int excl = hist[tid] - h0;
    __syncthreads();
    hist[tid] = excl;
    __syncthreads();
    #pragma unroll
    for (int k = 0; k < 4; ++k) {
        int pos = atomicAdd(&hist[key[k]], 1);
        dst[cb + pos] = p[k];
    }
}

__device__ __forceinline__ int zsearch(const float4* __restrict__ col,
                                       float t, bool strict, int lane) {
    float z1 = col[lane * 64].z;
    bool p1 = strict ? (z1 < t) : (z1 <= t);
    int s = __popcll(__ballot(p1));
    int base = (s == 0) ? 0 : (s - 1) * 64;
    float z2 = col[base + lane].z;
    bool p2 = strict ? (z2 < t) : (z2 <= t);
    return base + __popcll(__ballot(p2));
}

// ---------------- fill: z-pruned scan + jbuf epilogue, inits u/v ------------
__global__ __launch_bounds__(1024) void fill_kernel(
        const float4* __restrict__ A4s, const float4* __restrict__ B4s,
        u32* __restrict__ ee, int* __restrict__ cnt,
        float* __restrict__ u, float* __restrict__ v, int rcapLog) {
    __shared__ float4 tile[PHCOLS];              // 32 KB
    __shared__ u16 jbuf[16 * 1024];              // 32 KB
    int tid = threadIdx.x, wave = tid >> 6, lane = tid & 63;
    int bid = blockIdx.x;
    int dir = bid >> 10;
    int rbase = (bid & 1023) * 16;
    int b = rbase >> 12;
    const float4* Row = dir ? B4s : A4s;
    const float4* Col = dir ? A4s : B4s;
    const float4* Cb = Col + b * NPTS;
    int r = rbase + wave;
    int rd = dir * NROWS + r;
    float4 a = Row[r];
    u32 outbase = (u32)rd << rcapLog;
    float zlo = Row[rbase].z, zhi = Row[rbase + 15].z;
    int jlo = zsearch(Cb, zlo - ZMARG, true,  lane);
    int jhi = zsearch(Cb, zhi + ZMARG, false, lane);
    jlo = (jlo > 64 ? jlo - 64 : 0) & ~63;
    jhi = jhi + 64 > NPTS ? NPTS : jhi + 64;
    int phStart = jlo >> 11;
    int phEnd = (jhi + PHCOLS - 1) >> 11;
    int o = 0;
    u16* jb = jbuf + wave * 1024;
    for (int ph = phStart; ph < phEnd; ++ph) {
        __syncthreads();
        tile[tid]        = Cb[ph * PHCOLS + tid];
        tile[tid + 1024] = Cb[ph * PHCOLS + tid + 1024];
        __syncthreads();
        int gs = ph * PHCOLS; if (gs < jlo) gs = jlo;
        int ge = (ph + 1) * PHCOLS; if (ge > jhi) ge = (jhi + 63) & ~63;
        int pc = 0;
        for (int jt = gs; jt < ge; jt += 64) {
            float4 g = tile[jt - ph * PHCOLS + lane];
            bool keep = quad_d2(a, g) < THR;
            ull m = __ballot(keep);
            if (keep) {
                int pre = __builtin_amdgcn_mbcnt_hi((unsigned)(m >> 32),
                           __builtin_amdgcn_mbcnt_lo((unsigned)m, 0));
                int idx = pc + pre;
                if (idx < 1024) jb[idx] = (u16)(jt - ph * PHCOLS + lane);
            }
            pc += __popcll(m);
        }
        if (pc > 1024) pc = 1024;
        for (int t = lane; t < pc; t += 64) {
            int jl = jb[t];
            float4 g = tile[jl];
            float d2 = quad_d2(a, g);
            float d = __builtin_amdgcn_sqrtf(fmaxf(d2, 0.0f));
            u32 dq = (u32)fmaf(d, DSCALE, 0.5f);
            ee[outbase + (o + t)] = (dq << 16) | (u32)(ph * PHCOLS + jl);
        }
        o += pc;
    }
    if (lane == 0) cnt[rd] = o;                  // o <= 985 < rcap
    if (tid < 16) {
        int rr = rbase + tid;
        if (dir == 0) u[rr] = 1.0f; else v[rr] = 1.0f;
    }
}

// ---------------- Sinkhorn half-iteration: batched-prefetch walk ------------
// grid 2048 x block 256; strided row assignment (balance under z-sort).
// All 8 group-loads issued before use (rcap-padded rows make wrap reads safe);
// out-of-range values cndmask'd to DUMMY (sim==0) -> no serial tail.
__global__ __launch_bounds__(256) void pass_kernel(
        const int* __restrict__ cnt, int dir, const u32* __restrict__ ee,
        float* __restrict__ target, const float* __restrict__ source, int rcapLog) {
    __shared__ float ss[NPTS];                   // 16 KB
    int tid = threadIdx.x;
    int lb = blockIdx.x & 511;                   // local block within batch
    int b = blockIdx.x >> 9;
    #pragma unroll
    for (int k = 0; k < 4; ++k)
        ((float4*)ss)[tid + k*256] = ((const float4*)(source + b*NPTS))[tid + k*256];
    __syncthreads();
    int wave = tid >> 6, lane = tid & 63;
    int rmask = (1 << rcapLog) - 1;
    for (int rr = 0; rr < 2; ++rr) {
        int rloc = __builtin_amdgcn_readfirstlane(lb + 512 * (wave*2 + rr));
        int r = b * NPTS + rloc;
        int rd = dir * NROWS + r;
        int n = cnt[rd];
        u32 base = (u32)rd << rcapLog;
        float ac0 = 0.f, ac1 = 0.f;
        for (int tb = 0; tb < n; tb += 512) {
            u32 ev[8];
            #pragma unroll
            for (int g = 0; g < 8; ++g) {
                int t = tb + g*64 + lane;
                ev[g] = ee[base + (t & rmask)]; // always in-bounds (padded rows)
            }
            #pragma unroll
            for (int g = 0; g < 8; ++g) {
                int t = tb + g*64 + lane;
                u32 e = (t < n) ? ev[g] : DUMMY;
                float h = __builtin_amdgcn_exp2f((float)(e >> 16) * CDQ);
                if (g & 1) ac1 = fmaf(h * h, ss[e & 0xFFFF], ac1);
                else       ac0 = fmaf(h * h, ss[e & 0xFFFF], ac0);
            }
        }
        float acc = ac0 + ac1;
        #pragma unroll
        for (int off = 32; off > 0; off >>= 1) acc += __shfl_xor(acc, off);
        float to = target[r];
        float tn = to / fmaf(to, acc, EPSV);
        if (lane == 0) target[r] = tn;
    }
}

// ---------------- final: batched-prefetch top-5, strided rows ---------------
__global__ __launch_bounds__(256) void final_kernel(
        const int* __restrict__ cnt, const u32* __restrict__ ee,
        const float* __restrict__ u, const float* __restrict__ v,
        float* __restrict__ partial, int rcapLog) {
    __shared__ float vs[NPTS];                   // 16 KB
    __shared__ float wpart[4];
    int tid = threadIdx.x;
    int lb = blockIdx.x & 255;                   // grid 1024: 256 blocks/batch
    int b = blockIdx.x >> 8;
    #pragma unroll
    for (int k = 0; k < 4; ++k)
        ((float4*)vs)[tid + k*256] = ((const float4*)(v + b*NPTS))[tid + k*256];
    __syncthreads();
    int wave = tid >> 6, lane = tid & 63;
    int rmask = (1 << rcapLog) - 1;
    float wsum = 0.0f;
    for (int rr = 0; rr < 4; ++rr) {
        int rloc = __builtin_amdgcn_readfirstlane(lb + 256 * (wave*4 + rr));
        int r = b * NPTS + rloc;
        int n = cnt[r];                          // dir-A rows
        u32 base = (u32)r << rcapLog;
        float q0=-1.f,q1=-1.f,q2=-1.f,q3=-1.f,q4=-1.f;
        float d0=0.f,d1=0.f,d2v=0.f,d3=0.f,d4=0.f;
        for (int tb = 0; tb < n; tb += 512) {
            u32 ev[8];
            #pragma unroll
            for (int g = 0; g < 8; ++g) {
                int t = tb + g*64 + lane;
                ev[g] = ee[base + (t & rmask)];
            }
            #pragma unroll
            for (int g = 0; g < 8; ++g) {
                int t = tb + g*64 + lane;
                u32 ea = (t < n) ? ev[g] : DUMMY;
                float fdq = (float)(ea >> 16);
                float h = __builtin_amdgcn_exp2f(fdq * CDQ);
                float q = (h * h) * vs[ea & 0xFFFF];
                if (q > q4) {                    // dummy q=0 never beats real q>0
                    float dv = fdq * DINV;
                    q4 = q; d4 = dv;
                    if (q4 > q3) { float t1=q3;q3=q4;q4=t1; float t2=d3;d3=d4;d4=t2; }
                    if (q3 > q2) { float t1=q2;q2=q3;q3=t1; float t2=d2v;d2v=d3;d3=t2; }
                    if (q2 > q1) { float t1=q1;q1=q2;q2=t1; float t2=d1;d1=d2v;d2v=t2; }
                    if (q1 > q0) { float t1=q0;q0=q1;q1=t1; float t2=d0;d0=d1;d1=t2; }
                }
            }
        }
        float S0 = 0.0f, S1 = 0.0f;
        #define TOURN_ROUND                                                  \
        {                                                                    \
            float mq = q0, md = d0;                                          \
            _Pragma("unroll")                                                \
            for (int off = 1; off < 64; off <<= 1) {                         \
                float oq = __shfl_xor(mq, off), od = __shfl_xor(md, off);    \
                if (oq > mq) { mq = oq; md = od; }                           \
            }                                                                \
            if (mq > 0.0f) { S0 += mq; S1 = fmaf(mq, md, S1); }              \
            ull ball = __ballot(q0 == mq);                                   \
            int winner = __ffsll(ball) - 1;                                  \
            if (lane == winner) {                                            \
                q0=q1; d0=d1; q1=q2; d1=d2v; q2=q3; d2v=d3; q3=q4; d3=d4;    \
                q4=-1.f; d4=0.f;                                             \
            }                                                                \
        }
        TOURN_ROUND TOURN_ROUND TOURN_ROUND TOURN_ROUND TOURN_ROUND
        #undef TOURN_ROUND
        float uo = u[r];
        wsum += (uo * S1) / fmaf(uo, S0, EPSV);
    }
    if (lane == 0) wpart[wave] = wsum;
    __syncthreads();
    if (tid == 0)
        partial[blockIdx.x] = ((wpart[0] + wpart[1]) + wpart[2]) + wpart[3];
}

// ---------------- reduce: 1024 partials -> out[0] ---------------------------
__global__ void reduce_kernel(const float* __restrict__ partial,
                              float* __restrict__ out) {
    __shared__ float ws[4];
    int tid = threadIdx.x;                       // 1 block, 256 threads
    float s = ((partial[tid] + partial[tid+256]) +
               (partial[tid+512] + partial[tid+768]));
    #pragma unroll
    for (int off = 32; off > 0; off >>= 1) s += __shfl_xor(s, off);
    if ((tid & 63) == 0) ws[tid >> 6] = s;
    __syncthreads();
    if (tid == 0) out[0] = (((ws[0] + ws[1]) + ws[2]) + ws[3]) * (1.0f / NB);
}

extern "C" void kernel_launch(void* const* d_in, const int* in_sizes, int n_in,
                              void* d_out, int out_size, void* d_ws, size_t ws_size,
                              hipStream_t stream) {
    (void)in_sizes; (void)n_in; (void)out_size;
    const float* pred = (const float*)d_in[0];
    const float* gt   = (const float*)d_in[1];
    char* p = (char*)d_ws;

    float*  u       = (float*)p;    p += 65536;
    float*  v       = (float*)p;    p += 65536;
    int*    cnt     = (int*)p;      p += 131072;             // 32768 ints
    float*  partial = (float*)p;    p += 4096;               // 1024 floats
    float4* A4s     = (float4*)p;   p += 262144;             // 16384 float4
    float4* B4s     = (float4*)p;   p += 262144;
    u32*    ee      = (u32*)p;
    size_t fixed    = (size_t)(p - (char*)d_ws);
    int rcapLog = (ws_size >= fixed + (size_t)2*NROWS*1024*4) ? 10 : 9;
    float* out = (float*)d_out;

    hipLaunchKernelGGL(sort_kernel, dim3(8), dim3(1024), 0, stream,
                       pred, gt, A4s, B4s);
    hipLaunchKernelGGL(fill_kernel, dim3(2048), dim3(1024), 0, stream,
                       A4s, B4s, ee, cnt, u, v, rcapLog);
    for (int it = 0; it < 5; ++it) {
        hipLaunchKernelGGL(pass_kernel, dim3(2048), dim3(256), 0, stream,
                           cnt, 0, ee, u, v, rcapLog);   // row: u <- f(u; v)
        hipLaunchKernelGGL(pass_kernel, dim3(2048), dim3(256), 0, stream,
                           cnt, 1, ee, v, u, rcapLog);   // col: v <- f(v; u)
    }
    hipLaunchKernelGGL(final_kernel, dim3(1024), dim3(256), 0, stream,
                       cnt, ee, u, v, partial, rcapLog);
    hipLaunchKernelGGL(reduce_kernel, dim3(1), dim3(256), 0, stream, partial, out);
}

// Round 17
// 228.089 us; speedup vs baseline: 1.0412x; 1.0412x over previous
//
#include <hip/hip_runtime.h>

#define NPTS 4096
#define NB 4
#define NROWS (NB*NPTS)       // 16384
#define EPSV 1e-5f
#define THR 1.067f            // d2 cutoff: sim==+0.0 exactly for d2>1.0667 (h^2 underflow)
#define C2 (-72.134752f)      // -50*log2(e); sim = (2^(C2*d))^2 = exp(-100 d)
#define DSCALE 61900.0f       // d in [0,1.0333) -> u16 (max 63958)
#define DINV (1.0f/61900.0f)
#define CDQ (C2*DINV)         // exp2 arg per d_q count
#define ZMARG 1.05f           // z prune margin: sqrt(1.067)=1.033 + bin disorder
#define PHCOLS 2048           // columns per fill tile phase

typedef unsigned short u16;
typedef unsigned int u32;
typedef unsigned long long ull;

__device__ __forceinline__ float quad_d2(float4 a, float4 g) {
    float cr = fmaf(a.z, g.z, fmaf(a.y, g.y, a.x * g.x));
    return fmaf(-2.0f, cr, a.w + g.w);  // pinned FMA pattern, identical everywhere
}

// ---------------- sort: per batch+side, counting-sort by z, pack float4 -----
__global__ __launch_bounds__(1024) void sort_kernel(
        const float* __restrict__ pred, const float* __restrict__ gt,
        float4* __restrict__ A4s, float4* __restrict__ B4s) {
    __shared__ int hist[1024];
    int tid = threadIdx.x;
    int b = blockIdx.x >> 1, side = blockIdx.x & 1;
    const float* src = side ? gt : pred;
    float4* dst = side ? B4s : A4s;
    int cb = b * NPTS;
    float4 p[4]; int key[4];
    hist[tid] = 0;
    __syncthreads();
    #pragma unroll
    for (int k = 0; k < 4; ++k) {
        int idx = cb + k*1024 + tid;
        float x = src[3*idx], y = src[3*idx+1], z = src[3*idx+2];
        p[k] = make_float4(x, y, z, (x*x + y*y) + z*z);
        key[k] = (int)fminf(fmaxf((z + 5.0f) * 102.3f, 0.0f), 1023.0f);
        atomicAdd(&hist[key[k]], 1);
    }
    __syncthreads();
    int h0 = hist[tid];
    __syncthreads();
    for (int off = 1; off < 1024; off <<= 1) {
        int x = (tid >= off) ? hist[tid - off] : 0;
        __syncthreads();
        hist[tid] += x;
        __syncthreads();
    }
    int excl = hist[tid] - h0;
    __syncthreads();
    hist[tid] = excl;
    __syncthreads();
    #pragma unroll
    for (int k = 0; k < 4; ++k) {
        int pos = atomicAdd(&hist[key[k]], 1);
        dst[cb + pos] = p[k];
    }
}

__device__ __forceinline__ int zsearch(const float4* __restrict__ col,
                                       float t, bool strict, int lane) {
    float z1 = col[lane * 64].z;
    bool p1 = strict ? (z1 < t) : (z1 <= t);
    int s = __popcll(__ballot(p1));
    int base = (s == 0) ? 0 : (s - 1) * 64;
    float z2 = col[base + lane].z;
    bool p2 = strict ? (z2 < t) : (z2 <= t);
    return base + __popcll(__ballot(p2));
}

// ---------------- fill: z-pruned scan + jbuf epilogue, inits u/v ------------
// grid 2048 x block 1024: 16 contiguous sorted rows/block (tight z-window).
__global__ __launch_bounds__(1024) void fill_kernel(
        const float4* __restrict__ A4s, const float4* __restrict__ B4s,
        u32* __restrict__ ee, int* __restrict__ cnt,
        float* __restrict__ u, float* __restrict__ v, int rcapLog) {
    __shared__ float4 tile[PHCOLS];              // 32 KB
    __shared__ u16 jbuf[16 * 1024];              // 32 KB
    int tid = threadIdx.x, wave = tid >> 6, lane = tid & 63;
    int bid = blockIdx.x;
    int dir = bid >> 10;
    int rbase = (bid & 1023) * 16;
    int b = rbase >> 12;
    const float4* Row = dir ? B4s : A4s;
    const float4* Col = dir ? A4s : B4s;
    const float4* Cb = Col + b * NPTS;
    int r = rbase + wave;
    int rd = dir * NROWS + r;
    float4 a = Row[r];
    u32 outbase = (u32)rd << rcapLog;
    float zlo = Row[rbase].z, zhi = Row[rbase + 15].z;
    int jlo = zsearch(Cb, zlo - ZMARG, true,  lane);
    int jhi = zsearch(Cb, zhi + ZMARG, false, lane);
    jlo = (jlo > 64 ? jlo - 64 : 0) & ~63;
    jhi = jhi + 64 > NPTS ? NPTS : jhi + 64;
    int phStart = jlo >> 11;
    int phEnd = (jhi + PHCOLS - 1) >> 11;
    int o = 0;
    u16* jb = jbuf + wave * 1024;
    for (int ph = phStart; ph < phEnd; ++ph) {
        __syncthreads();
        tile[tid]        = Cb[ph * PHCOLS + tid];
        tile[tid + 1024] = Cb[ph * PHCOLS + tid + 1024];
        __syncthreads();
        int gs = ph * PHCOLS; if (gs < jlo) gs = jlo;
        int ge = (ph + 1) * PHCOLS; if (ge > jhi) ge = (jhi + 63) & ~63;
        int pc = 0;
        for (int jt = gs; jt < ge; jt += 64) {
            float4 g = tile[jt - ph * PHCOLS + lane];
            bool keep = quad_d2(a, g) < THR;
            ull m = __ballot(keep);
            if (keep) {
                int pre = __builtin_amdgcn_mbcnt_hi((unsigned)(m >> 32),
                           __builtin_amdgcn_mbcnt_lo((unsigned)m, 0));
                int idx = pc + pre;
                if (idx < 1024) jb[idx] = (u16)(jt - ph * PHCOLS + lane);
            }
            pc += __popcll(m);
        }
        if (pc > 1024) pc = 1024;
        for (int t = lane; t < pc; t += 64) {
            int jl = jb[t];
            float4 g = tile[jl];
            float d2 = quad_d2(a, g);
            float d = __builtin_amdgcn_sqrtf(fmaxf(d2, 0.0f));
            u32 dq = (u32)fmaf(d, DSCALE, 0.5f);
            ee[outbase + (o + t)] = (dq << 16) | (u32)(ph * PHCOLS + jl);
        }
        o += pc;
    }
    if (lane == 0) cnt[rd] = o;                  // o <= 985 < rcap
    if (tid < 16) {
        int rr = rbase + tid;
        if (dir == 0) u[rr] = 1.0f; else v[rr] = 1.0f;
    }
}

// ---------------- Sinkhorn half-iteration: wave-per-row, strided rows -------
// grid 1024 x block 512: 16 rows/block (strided by 256 across sorted order ->
// every block mixes degree classes), 2 rows/wave, 4 blocks/CU = 32 waves/CU.
__global__ __launch_bounds__(512) void pass_kernel(
        const int* __restrict__ cnt, int dir, const u32* __restrict__ ee,
        float* __restrict__ target, const float* __restrict__ source, int rcapLog) {
    __shared__ float ss[NPTS];                   // 16 KB
    int tid = threadIdx.x;
    int lb = blockIdx.x & 255;                   // 256 blocks per batch
    int b = blockIdx.x >> 8;
    #pragma unroll
    for (int k = 0; k < 2; ++k)
        ((float4*)ss)[tid + k*512] = ((const float4*)(source + b*NPTS))[tid + k*512];
    __syncthreads();
    int wave = tid >> 6, lane = tid & 63;
    for (int rr = 0; rr < 2; ++rr) {
        int rloc = __builtin_amdgcn_readfirstlane(lb + 256 * (wave*2 + rr));
        int rd = dir * NROWS + b * NPTS + rloc;
        int n = cnt[rd];
        u32 base = (u32)rd << rcapLog;
        float ac0 = 0.f, ac1 = 0.f, ac2 = 0.f, ac3 = 0.f;
        int t = lane;
        for (; t + 192 < n; t += 256) {          // 4-way MLP
            u32 e0 = ee[base+t], e1 = ee[base+t+64], e2 = ee[base+t+128], e3 = ee[base+t+192];
            float h0 = __builtin_amdgcn_exp2f((float)(e0 >> 16) * CDQ);
            float h1 = __builtin_amdgcn_exp2f((float)(e1 >> 16) * CDQ);
            float h2 = __builtin_amdgcn_exp2f((float)(e2 >> 16) * CDQ);
            float h3 = __builtin_amdgcn_exp2f((float)(e3 >> 16) * CDQ);
            ac0 = fmaf(h0 * h0, ss[e0 & 0xFFFF], ac0);
            ac1 = fmaf(h1 * h1, ss[e1 & 0xFFFF], ac1);
            ac2 = fmaf(h2 * h2, ss[e2 & 0xFFFF], ac2);
            ac3 = fmaf(h3 * h3, ss[e3 & 0xFFFF], ac3);
        }
        for (; t < n; t += 64) {
            u32 e0 = ee[base+t];
            float h0 = __builtin_amdgcn_exp2f((float)(e0 >> 16) * CDQ);
            ac0 = fmaf(h0 * h0, ss[e0 & 0xFFFF], ac0);
        }
        float acc = (ac0 + ac1) + (ac2 + ac3);
        #pragma unroll
        for (int off = 32; off > 0; off >>= 1) acc += __shfl_xor(acc, off);
        int r = b * NPTS + rloc;
        float to = target[r];
        float tn = to / fmaf(to, acc, EPSV);
        if (lane == 0) target[r] = tn;
    }
}

// ---------------- final: wave-per-row top-5, strided rows -------------------
// grid 512 x block 512: 32 rows/block (strided by 128), 4 rows/wave.
__global__ __launch_bounds__(512) void final_kernel(
        const int* __restrict__ cnt, const u32* __restrict__ ee,
        const float* __restrict__ u, const float* __restrict__ v,
        float* __restrict__ partial, int rcapLog) {
    __shared__ float vs[NPTS];                   // 16 KB
    __shared__ float wpart[8];
    int tid = threadIdx.x;
    int lb = blockIdx.x & 127;                   // 128 blocks per batch
    int b = blockIdx.x >> 7;
    #pragma unroll
    for (int k = 0; k < 2; ++k)
        ((float4*)vs)[tid + k*512] = ((const float4*)(v + b*NPTS))[tid + k*512];
    __syncthreads();
    int wave = tid >> 6, lane = tid & 63;
    float wsum = 0.0f;
    for (int rr = 0; rr < 4; ++rr) {
        int rloc = __builtin_amdgcn_readfirstlane(lb + 128 * (wave*4 + rr));
        int r = b * NPTS + rloc;
        int n = cnt[r];                          // dir-A rows
        u32 base = (u32)r << rcapLog;
        float q0=-1.f,q1=-1.f,q2=-1.f,q3=-1.f,q4=-1.f;
        float d0=0.f,d1=0.f,d2v=0.f,d3=0.f,d4=0.f;
        for (int t = lane; t < n; t += 64) {
            u32 ea = ee[base + t];
            float fdq = (float)(ea >> 16);
            float h = __builtin_amdgcn_exp2f(fdq * CDQ);
            float q = (h * h) * vs[ea & 0xFFFF];
            if (q > q4) {                        // pure-VALU insert
                float dv = fdq * DINV;
                q4 = q; d4 = dv;
                if (q4 > q3) { float t1=q3;q3=q4;q4=t1; float t2=d3;d3=d4;d4=t2; }
                if (q3 > q2) { float t1=q2;q2=q3;q3=t1; float t2=d2v;d2v=d3;d3=t2; }
                if (q2 > q1) { float t1=q1;q1=q2;q2=t1; float t2=d1;d1=d2v;d2v=t2; }
                if (q1 > q0) { float t1=q0;q0=q1;q1=t1; float t2=d0;d0=d1;d1=t2; }
            }
        }
        float S0 = 0.0f, S1 = 0.0f;
        #define TOURN_ROUND                                                  \
        {                                                                    \
            float mq = q0, md = d0;                                          \
            _Pragma("unroll")                                                \
            for (int off = 1; off < 64; off <<= 1) {                         \
                float oq = __shfl_xor(mq, off), od = __shfl_xor(md, off);    \
                if (oq > mq) { mq = oq; md = od; }                           \
            }                                                                \
            if (mq > 0.0f) { S0 += mq; S1 = fmaf(mq, md, S1); }              \
            ull ball = __ballot(q0 == mq);                                   \
            int winner = __ffsll(ball) - 1;                                  \
            if (lane == winner) {                                            \
                q0=q1; d0=d1; q1=q2; d1=d2v; q2=q3; d2v=d3; q3=q4; d3=d4;    \
                q4=-1.f; d4=0.f;                                             \
            }                                                                \
        }
        TOURN_ROUND TOURN_ROUND TOURN_ROUND TOURN_ROUND TOURN_ROUND
        #undef TOURN_ROUND
        float uo = u[r];
        wsum += (uo * S1) / fmaf(uo, S0, EPSV);
    }
    if (lane == 0) wpart[wave] = wsum;
    __syncthreads();
    if (tid == 0) {
        float s = 0.0f;
        #pragma unroll
        for (int i = 0; i < 8; ++i) s += wpart[i];
        partial[blockIdx.x] = s;
    }
}

// ---------------- reduce: 512 partials -> out[0] ----------------------------
__global__ void reduce_kernel(const float* __restrict__ partial,
                              float* __restrict__ out) {
    __shared__ float ws[4];
    int tid = threadIdx.x;                       // 1 block, 256 threads
    float s = partial[tid] + partial[tid + 256];
    #pragma unroll
    for (int off = 32; off > 0; off >>= 1) s += __shfl_xor(s, off);
    if ((tid & 63) == 0) ws[tid >> 6] = s;
    __syncthreads();
    if (tid == 0) out[0] = (((ws[0] + ws[1]) + ws[2]) + ws[3]) * (1.0f / NB);
}

extern "C" void kernel_launch(void* const* d_in, const int* in_sizes, int n_in,
                              void* d_out, int out_size, void* d_ws, size_t ws_size,
                              hipStream_t stream) {
    (void)in_sizes; (void)n_in; (void)out_size;
    const float* pred = (const float*)d_in[0];
    const float* gt   = (const float*)d_in[1];
    char* p = (char*)d_ws;

    float*  u       = (float*)p;    p += 65536;
    float*  v       = (float*)p;    p += 65536;
    int*    cnt     = (int*)p;      p += 131072;             // 32768 ints
    float*  partial = (float*)p;    p += 4096;               // 512 floats + pad
    float4* A4s     = (float4*)p;   p += 262144;             // 16384 float4
    float4* B4s     = (float4*)p;   p += 262144;
    u32*    ee      = (u32*)p;
    size_t fixed    = (size_t)(p - (char*)d_ws);
    int rcapLog = (ws_size >= fixed + (size_t)2*NROWS*1024*4) ? 10 : 9;
    float* out = (float*)d_out;

    hipLaunchKernelGGL(sort_kernel, dim3(8), dim3(1024), 0, stream,
                       pred, gt, A4s, B4s);
    hipLaunchKernelGGL(fill_kernel, dim3(2048), dim3(1024), 0, stream,
                       A4s, B4s, ee, cnt, u, v, rcapLog);
    for (int it = 0; it < 5; ++it) {
        hipLaunchKernelGGL(pass_kernel, dim3(1024), dim3(512), 0, stream,
                           cnt, 0, ee, u, v, rcapLog);   // row: u <- f(u; v)
        hipLaunchKernelGGL(pass_kernel, dim3(1024), dim3(512), 0, stream,
                           cnt, 1, ee, v, u, rcapLog);   // col: v <- f(v; u)
    }
    hipLaunchKernelGGL(final_kernel, dim3(512), dim3(512), 0, stream,
                       cnt, ee, u, v, partial, rcapLog);
    hipLaunchKernelGGL(reduce_kernel, dim3(1), dim3(256), 0, stream, partial, out);
}